// Round 2
// baseline (2554.189 us; speedup 1.0000x reference)
//
#include <hip/hip_runtime.h>
#include <hip/hip_bf16.h>

typedef unsigned short u16;

#define B_    4
#define T_    7
#define C_    64
#define C2_   32
#define HW_   4096
#define KF_   224            // C2_*T_
#define NTOT_ 28672          // T_*HW_

// ---------------- bf16 helpers ----------------------------------------------
__device__ __forceinline__ float bf2f(u16 v){ return __uint_as_float(((unsigned)v)<<16); }
__device__ __forceinline__ u16 f2bf(float f){
  unsigned u = __float_as_uint(f);
  u = u + 0x7fffu + ((u>>16)&1u);   // round-to-nearest-even
  return (u16)(u>>16);
}

// ---------------- workspace layout (bytes) ----------------------------------
static const size_t OFF_TH_HW=0;                 // bf16 [B][224][4096]  (k-major)
static const size_t OFF_PH_HW=7340032;           // bf16
static const size_t OFF_G_HW =14680064;          // bf16
static const size_t OFF_Y_HW =22020096;          // bf16 attention output
static const size_t OFF_TH_T =29360128;          // f32  [B][224][4096]
static const size_t OFF_PH_T =44040192;          // f32
static const size_t OFF_GRAM =58720256;          // f32 [B][64][64]  (atomics)
static const size_t OFF_SROW =58785792;          // f32 [B][64]      (atomics)
static const size_t OFF_LT   =58786816;          // f32 [B][7][7]
static const size_t OFF_MC   =58787840;          // f32 [B][64][64]
static const size_t OFF_VC   =58853376;          // f32 [B][64]
static const size_t OFF_MT   =58854400;          // f32 [64][64]
static const size_t OFF_VT   =58870784;          // f32 [64]

// ============================================================================
// K1: 5 channel-mix projections per (b,t,hw) location (f32 in).
//     proj 0..2 = hw theta/phi/g  -> bf16 k-major [B][c2*T][hw]
//     proj 3..4 = t  theta/phi    -> f32  k-major (precision for T-softmax)
// ============================================================================
__global__ __launch_bounds__(256) void k1_proj(
    const float* __restrict__ x,
    const float* w0,const float* bb0,const float* w1,const float* bb1,
    const float* w2,const float* bb2,const float* w3,const float* bb3,
    const float* w4,const float* bb4,
    u16* o0,u16* o1,u16* o2,float* o3,float* o4)
{
  __shared__ float wsm[5][C2_][C_];
  __shared__ float bsm[5][C2_];
  const float* wp[5]={w0,w1,w2,w3,w4};
  const float* bp[5]={bb0,bb1,bb2,bb3,bb4};
  int tid=threadIdx.x;
  for(int e=tid;e<5*C2_*C_;e+=256){ int pr=e>>11; int rc=e&2047; wsm[pr][rc>>6][rc&63]=wp[pr][rc]; }
  if(tid<5*C2_) bsm[tid>>5][tid&31]=bp[tid>>5][tid&31];
  __syncthreads();
  int bi=blockIdx.x;
  int b=bi/112, r=bi%112, t=r>>4;
  int p=((r&15)<<8)+tid;
  const float* xp = x + (((long)(b*T_+t))*C_)*HW_ + p;
  float xc[C_];
  #pragma unroll
  for(int c=0;c<C_;c++) xc[c]=xp[(long)c*HW_];
  long obase = ((long)b*KF_ + t)*HW_ + p;

  for(int pr=0;pr<5;pr++){
    for(int c2=0;c2<C2_;c2++){
      float acc=bsm[pr][c2];
      const float4* wr=(const float4*)wsm[pr][c2];
      #pragma unroll
      for(int q=0;q<16;q++){ float4 w4=wr[q];
        acc+=w4.x*xc[q*4]+w4.y*xc[q*4+1]+w4.z*xc[q*4+2]+w4.w*xc[q*4+3]; }
      long oa = obase + (long)(c2*T_)*HW_;
      if(pr==0) o0[oa]=f2bf(acc);
      else if(pr==1) o1[oa]=f2bf(acc);
      else if(pr==2) o2[oa]=f2bf(acc);
      else if(pr==3) o3[oa]=acc;
      else           o4[oa]=acc;
    }
  }
}

// ============================================================================
// K2: HW attention (the 60-GFLOP hot kernel), bf16 in / bf16 out.
//     Per block: 64 queries (p0..p0+63), stream 4096 keys in tiles of 32.
//     No max-tracking: logits are small (|l| < ~20) so exp() is f32-safe.
// ============================================================================
#define PT_ 64
#define QT_ 32
__global__ __launch_bounds__(256) void k2_attn(
    const u16* __restrict__ th_g, const u16* __restrict__ ph_g,
    const u16* __restrict__ g_g, u16* __restrict__ y_g)
{
  __shared__ __align__(16) u16  th_s[KF_][68];
  __shared__ __align__(16) u16  pg_s[KF_][36];
  __shared__ __align__(16) float S_s[QT_][68];
  __shared__ float den_s[PT_];
  int tid=threadIdx.x;
  int b=blockIdx.x>>6;
  int p0=(blockIdx.x&63)<<6;
  const u16* thb = th_g + ((long)b*KF_)*HW_ + p0;
  for(int e=tid;e<KF_*32;e+=256){ int k=e>>5, ii=e&31;
    *(ushort2*)&th_s[k][ii*2] = *(const ushort2*)&thb[(long)k*HW_ + ii*2]; }
  if(tid<PT_) den_s[tid]=0.f;

  float acc[14][4];
  #pragma unroll
  for(int m=0;m<14;m++){acc[m][0]=0.f;acc[m][1]=0.f;acc[m][2]=0.f;acc[m][3]=0.f;}
  int ig=tid&15, jg=tid>>4;     // S-phase: 4 queries x 2 keys per thread
  int kg=tid>>4, ig2=tid&15;    // PV-phase: 14 k-rows x 4 queries per thread

  for(int step=0; step<HW_/QT_; step++){
    int q0=step*QT_;
    __syncthreads();                         // prev PV done -> pg_s reusable
    { const u16* pb=ph_g+((long)b*KF_)*HW_+q0;
      for(int e=tid;e<KF_*16;e+=256){ int k=e>>4, jj=e&15;
        *(ushort2*)&pg_s[k][jj*2] = *(const ushort2*)&pb[(long)k*HW_+jj*2]; } }
    __syncthreads();
    // ---- S = exp(th^T ph) ----
    {
      int i0=ig*4, j0=jg*2;
      float s00=0,s01=0,s10=0,s11=0,s20=0,s21=0,s30=0,s31=0;
      #pragma unroll 4
      for(int k=0;k<KF_;k++){
        uint2 av=*(const uint2*)&th_s[k][i0];
        uint  bv=*(const uint*)&pg_s[k][j0];
        float a0=__uint_as_float(av.x<<16), a1=__uint_as_float(av.x&0xffff0000u);
        float a2=__uint_as_float(av.y<<16), a3=__uint_as_float(av.y&0xffff0000u);
        float b0=__uint_as_float(bv<<16),   b1=__uint_as_float(bv&0xffff0000u);
        s00+=a0*b0; s01+=a0*b1; s10+=a1*b0; s11+=a1*b1;
        s20+=a2*b0; s21+=a2*b1; s30+=a3*b0; s31+=a3*b1;
      }
      float4 c0=make_float4(__expf(s00),__expf(s10),__expf(s20),__expf(s30));
      float4 c1=make_float4(__expf(s01),__expf(s11),__expf(s21),__expf(s31));
      *(float4*)&S_s[j0  ][i0]=c0;
      *(float4*)&S_s[j0+1][i0]=c1;
    }
    __syncthreads();
    // ---- load g tile (overwrites ph); 64 threads also fold denominators ----
    { const u16* gb=g_g+((long)b*KF_)*HW_+q0;
      for(int e=tid;e<KF_*16;e+=256){ int k=e>>4, jj=e&15;
        *(ushort2*)&pg_s[k][jj*2] = *(const ushort2*)&gb[(long)k*HW_+jj*2]; } }
    if(tid<PT_){
      float s=0.f;
      #pragma unroll
      for(int j=0;j<QT_;j++) s+=S_s[j][tid];
      den_s[tid]+=s;
    }
    __syncthreads();
    // ---- PV: y[k][i] += sum_j g[k][j] * P[j][i] ----
    {
      int i0=ig2*4;
      #pragma unroll 2
      for(int jq=0;jq<QT_;jq+=4){
        float4 sv0=*(const float4*)&S_s[jq  ][i0];
        float4 sv1=*(const float4*)&S_s[jq+1][i0];
        float4 sv2=*(const float4*)&S_s[jq+2][i0];
        float4 sv3=*(const float4*)&S_s[jq+3][i0];
        #pragma unroll
        for(int m=0;m<14;m++){
          uint2 gv=*(const uint2*)&pg_s[kg*14+m][jq];
          float g0=__uint_as_float(gv.x<<16), g1=__uint_as_float(gv.x&0xffff0000u);
          float g2=__uint_as_float(gv.y<<16), g3=__uint_as_float(gv.y&0xffff0000u);
          acc[m][0]+=g0*sv0.x+g1*sv1.x+g2*sv2.x+g3*sv3.x;
          acc[m][1]+=g0*sv0.y+g1*sv1.y+g2*sv2.y+g3*sv3.y;
          acc[m][2]+=g0*sv0.z+g1*sv1.z+g2*sv2.z+g3*sv3.z;
          acc[m][3]+=g0*sv0.w+g1*sv1.w+g2*sv2.w+g3*sv3.w;
        }
      }
    }
  }
  __syncthreads();
  {
    int i0=ig2*4;
    float inv0=1.f/den_s[i0], inv1=1.f/den_s[i0+1], inv2=1.f/den_s[i0+2], inv3=1.f/den_s[i0+3];
    u16* yb=y_g+((long)b*KF_+kg*14)*HW_+p0+i0;
    #pragma unroll
    for(int m=0;m<14;m++){
      ushort4 o4;
      o4.x=f2bf(acc[m][0]*inv0); o4.y=f2bf(acc[m][1]*inv1);
      o4.z=f2bf(acc[m][2]*inv2); o4.w=f2bf(acc[m][3]*inv3);
      *(ushort4*)&yb[(long)m*HW_]=o4;
    }
  }
}

// ============================================================================
// K3: per-batch Gram G = X X^T (64x64) + row sums s = X 1  (f32 in)
// ============================================================================
__global__ __launch_bounds__(256) void k3_gram(const float* __restrict__ x,
                                               float* __restrict__ G, float* __restrict__ srow)
{
  __shared__ __align__(8) float xt[C_][68];
  int tid=threadIdx.x;
  int b=blockIdx.x>>6, ch=blockIdx.x&63;
  int ci0=(tid>>4)*4, cj0=(tid&15)*4;
  float acc[4][4];
  #pragma unroll
  for(int di=0;di<4;di++){acc[di][0]=0;acc[di][1]=0;acc[di][2]=0;acc[di][3]=0;}
  float sp=0.f;
  for(int st=0; st<7; st++){
    int n0=ch*448+st*64;
    int t=n0>>12, hw0=n0&4095;
    __syncthreads();
    for(int e=tid;e<C_*32;e+=256){ int c=e>>5, nn=e&31;
      *(float2*)&xt[c][nn*2]=*(const float2*)&x[(((long)(b*T_+t))*C_+c)*HW_+hw0+nn*2]; }
    __syncthreads();
    if(tid<C_){
      float s=0.f;
      for(int n=0;n<64;n++) s+=xt[tid][n];
      sp+=s;
    }
    for(int n=0;n<64;n++){
      float av[4],bv[4];
      #pragma unroll
      for(int d=0;d<4;d++){ av[d]=xt[ci0+d][n]; bv[d]=xt[cj0+d][n]; }
      #pragma unroll
      for(int di=0;di<4;di++)
        #pragma unroll
        for(int dj=0;dj<4;dj++)
          acc[di][dj]+=av[di]*bv[dj];
    }
  }
  float* Gb=G+b*4096;
  #pragma unroll
  for(int di=0;di<4;di++)
    #pragma unroll
    for(int dj=0;dj<4;dj++)
      atomicAdd(&Gb[(ci0+di)*64+cj0+dj], acc[di][dj]);
  if(tid<C_) atomicAdd(&srow[b*64+tid], sp);
}

// ============================================================================
// K4: per-batch C-branch collapse: Mc = Wz softmax(Wth G Wph^T + bias) Wg, vc.
//     Block 0 also builds T-branch Mt = Wz_t Wg_t, vt.
// ============================================================================
__global__ __launch_bounds__(256) void k4_prep(
  const float* __restrict__ G, const float* __restrict__ srow,
  const float* cthw,const float* cthb,const float* cphw,const float* cphb,
  const float* cgw,const float* cgb,const float* czw,const float* czb,
  const float* tgw,const float* tgb,const float* tzw,const float* tzb,
  float* Mc, float* vc, float* Mt, float* vt)
{
  __shared__ float Gl[64][65];
  __shared__ float A1[32][65];
  __shared__ float fl[32][33];
  __shared__ float B1[32][65];
  __shared__ float sv[64], uu[32], vv[32], fb[32];
  int tid=threadIdx.x, b=blockIdx.x;
  for(int e=tid;e<4096;e+=256) Gl[e>>6][e&63]=G[b*4096+e];
  if(tid<64) sv[tid]=srow[b*64+tid];
  __syncthreads();
  if(tid<32){
    float a=0,bp=0;
    for(int c=0;c<64;c++){ a+=cthw[tid*64+c]*sv[c]; bp+=cphw[tid*64+c]*sv[c]; }
    uu[tid]=a; vv[tid]=bp;
  }
  __syncthreads();
  for(int e=tid;e<2048;e+=256){ int i=e>>6,cp=e&63;
    float a=0;
    for(int c=0;c<64;c++) a+=cthw[i*64+c]*Gl[c][cp];
    A1[i][cp]=a;
  }
  __syncthreads();
  for(int e=tid;e<1024;e+=256){ int i=e>>5,j=e&31;
    float a=0;
    for(int cp=0;cp<64;cp++) a+=A1[i][cp]*cphw[j*64+cp];
    a+=uu[i]*cphb[j]+cthb[i]*vv[j]+(float)NTOT_*cthb[i]*cphb[j];
    fl[i][j]=a;
  }
  __syncthreads();
  if(tid<32){
    float m=-1e30f;
    for(int j=0;j<32;j++) m=fmaxf(m,fl[tid][j]);
    float s=0;
    for(int j=0;j<32;j++){ float e2=__expf(fl[tid][j]-m); fl[tid][j]=e2; s+=e2; }
    float inv=1.f/s;
    for(int j=0;j<32;j++) fl[tid][j]*=inv;
    float a=0;
    for(int j=0;j<32;j++) a+=fl[tid][j]*cgb[j];
    fb[tid]=a;
  }
  __syncthreads();
  for(int e=tid;e<2048;e+=256){ int i=e>>6,cp=e&63;
    float a=0;
    for(int j=0;j<32;j++) a+=fl[i][j]*cgw[j*64+cp];
    B1[i][cp]=a;
  }
  __syncthreads();
  for(int e=tid;e<4096;e+=256){ int c=e>>6,cp=e&63;
    float a=0;
    for(int i=0;i<32;i++) a+=czw[c*32+i]*B1[i][cp];
    Mc[b*4096+e]=a;
  }
  if(tid<64){
    float a=0;
    for(int i=0;i<32;i++) a+=czw[tid*32+i]*fb[i];
    vc[b*64+tid]=a+czb[tid];
  }
  if(b==0){
    for(int e=tid;e<4096;e+=256){ int c=e>>6,cp=e&63;
      float a=0;
      for(int i=0;i<32;i++) a+=tzw[c*32+i]*tgw[i*64+cp];
      Mt[e]=a;
    }
    if(tid<64){
      float a=0;
      for(int i=0;i<32;i++) a+=tzw[tid*32+i]*tgb[i];
      vt[tid]=a+tzb[tid];
    }
  }
}

// ============================================================================
// K5: T-branch raw logits L[b][t][s] = sum_{c2,hw} th_t . ph_t   (f32)
// ============================================================================
__global__ __launch_bounds__(256) void k5_tlogit(const float* __restrict__ th,
                                                 const float* __restrict__ ph,
                                                 float* __restrict__ Lt)
{
  __shared__ float wsum[4];
  int tid=threadIdx.x;
  int bi=blockIdx.x;
  int b=bi/49, r=bi%49, t=r/7, s=r%7;
  const float* A =th+((long)b*C2_*T_+t)*HW_;
  const float* Bp=ph+((long)b*C2_*T_+s)*HW_;
  float part=0.f;
  for(int c2=0;c2<C2_;c2++){
    const float4* a4=(const float4*)(A +(long)c2*T_*HW_);
    const float4* b4=(const float4*)(Bp+(long)c2*T_*HW_);
    #pragma unroll
    for(int rr=0;rr<4;rr++){
      int idx=rr*256+tid;
      float4 av=a4[idx], bv=b4[idx];
      part+=av.x*bv.x+av.y*bv.y+av.z*bv.z+av.w*bv.w;
    }
  }
  for(int off=32;off>0;off>>=1) part+=__shfl_down(part,off,64);
  if((tid&63)==0) wsum[tid>>6]=part;
  __syncthreads();
  if(tid==0) Lt[bi]=wsum[0]+wsum[1]+wsum[2]+wsum[3];
}

// ============================================================================
// K6: fused epilogue per (b,t,hw):
//   out = x + Wz_hw . y_hw + Mc . xcol + Mt . xbar + const
//   where xbar = sum_s softmax(L_t)[t][s] * x[b,s,:,hw]
// ============================================================================
__global__ __launch_bounds__(256) void k6_final(
  const float* __restrict__ x, const u16* __restrict__ y_hw,
  const float* __restrict__ Lt, const float* __restrict__ Mc, const float* __restrict__ vc,
  const float* __restrict__ Mt, const float* __restrict__ vt,
  const float* hzw, const float* hzb, float* __restrict__ out)
{
  __shared__ float Mcl[64][64];
  __shared__ float Mtl[64][64];
  __shared__ float Wzl[64][32];
  __shared__ float cst[64];
  __shared__ float ftr[8];
  __shared__ float raw[8];
  int tid=threadIdx.x;
  int bi=blockIdx.x;
  int b=bi/112, r=bi%112, t=r>>4;
  int p=((r&15)<<8)+tid;
  for(int e=tid;e<4096;e+=256){ Mcl[e>>6][e&63]=Mc[b*4096+e]; Mtl[e>>6][e&63]=Mt[e]; }
  for(int e=tid;e<2048;e+=256) Wzl[e>>5][e&31]=hzw[e];
  if(tid<64) cst[tid]=vc[b*64+tid]+vt[tid]+hzb[tid];
  if(tid<7) raw[tid]=Lt[b*49+t*7+tid];
  __syncthreads();
  if(tid==0){
    float m=-1e30f;
    for(int s=0;s<7;s++) m=fmaxf(m,raw[s]);
    float ssum=0.f; float e7[7];
    #pragma unroll
    for(int s=0;s<7;s++){ e7[s]=__expf(raw[s]-m); ssum+=e7[s]; }
    #pragma unroll
    for(int s=0;s<7;s++) ftr[s]=e7[s]/ssum;
  }
  __syncthreads();
  float xcol[64], xbar[64];
  #pragma unroll
  for(int c=0;c<64;c++) xbar[c]=0.f;
  for(int s=0;s<7;s++){
    float fs=ftr[s];
    const float* xp=x+(((long)(b*T_+s))*C_)*HW_+p;
    if(s==t){
      #pragma unroll
      for(int c=0;c<64;c++){ float v0=xp[(long)c*HW_]; xcol[c]=v0; xbar[c]+=fs*v0; }
    } else {
      #pragma unroll
      for(int c=0;c<64;c++){ float v0=xp[(long)c*HW_]; xbar[c]+=fs*v0; }
    }
  }
  float yv[32];
  const u16* yp=y_hw+((long)b*KF_+t)*HW_+p;
  #pragma unroll
  for(int c2=0;c2<32;c2++) yv[c2]=bf2f(yp[(long)(c2*T_)*HW_]);
  float* op=out+(((long)(b*T_+t))*C_)*HW_+p;
  #pragma unroll
  for(int c=0;c<64;c++){
    float a=xcol[c]+cst[c];
    const float4* wr=(const float4*)Wzl[c];
    #pragma unroll
    for(int q=0;q<8;q++){ float4 w4=wr[q];
      a+=w4.x*yv[q*4]+w4.y*yv[q*4+1]+w4.z*yv[q*4+2]+w4.w*yv[q*4+3]; }
    const float4* mr=(const float4*)Mcl[c];
    const float4* tr=(const float4*)Mtl[c];
    #pragma unroll
    for(int q=0;q<16;q++){
      float4 m4=mr[q], t4=tr[q];
      a+=m4.x*xcol[q*4]+m4.y*xcol[q*4+1]+m4.z*xcol[q*4+2]+m4.w*xcol[q*4+3];
      a+=t4.x*xbar[q*4]+t4.y*xbar[q*4+1]+t4.z*xbar[q*4+2]+t4.w*xbar[q*4+3];
    }
    op[(long)c*HW_]=a;
  }
}

// ============================================================================
extern "C" void kernel_launch(void* const* d_in, const int* in_sizes, int n_in,
                              void* d_out, int out_size, void* d_ws, size_t ws_size,
                              hipStream_t stream)
{
  (void)in_sizes; (void)n_in; (void)out_size; (void)ws_size;
  const float* x      =(const float*)d_in[0];
  const float* hw_th_w=(const float*)d_in[1];  const float* hw_th_b=(const float*)d_in[2];
  const float* hw_ph_w=(const float*)d_in[3];  const float* hw_ph_b=(const float*)d_in[4];
  const float* hw_g_w =(const float*)d_in[5];  const float* hw_g_b =(const float*)d_in[6];
  const float* hw_z_w =(const float*)d_in[7];  const float* hw_z_b =(const float*)d_in[8];
  const float* c_th_w =(const float*)d_in[9];  const float* c_th_b =(const float*)d_in[10];
  const float* c_ph_w =(const float*)d_in[11]; const float* c_ph_b =(const float*)d_in[12];
  const float* c_g_w  =(const float*)d_in[13]; const float* c_g_b  =(const float*)d_in[14];
  const float* c_z_w  =(const float*)d_in[15]; const float* c_z_b  =(const float*)d_in[16];
  const float* t_th_w =(const float*)d_in[17]; const float* t_th_b =(const float*)d_in[18];
  const float* t_ph_w =(const float*)d_in[19]; const float* t_ph_b =(const float*)d_in[20];
  const float* t_g_w  =(const float*)d_in[21]; const float* t_g_b  =(const float*)d_in[22];
  const float* t_z_w  =(const float*)d_in[23]; const float* t_z_b  =(const float*)d_in[24];

  char* wsb=(char*)d_ws;
  u16*   th_hw=(u16*)  (wsb+OFF_TH_HW);
  u16*   ph_hw=(u16*)  (wsb+OFF_PH_HW);
  u16*   g_hw =(u16*)  (wsb+OFF_G_HW);
  u16*   y_hw =(u16*)  (wsb+OFF_Y_HW);
  float* th_t =(float*)(wsb+OFF_TH_T);
  float* ph_t =(float*)(wsb+OFF_PH_T);
  float* G    =(float*)(wsb+OFF_GRAM);
  float* srow =(float*)(wsb+OFF_SROW);
  float* Lt   =(float*)(wsb+OFF_LT);
  float* Mc   =(float*)(wsb+OFF_MC);
  float* vc   =(float*)(wsb+OFF_VC);
  float* Mt   =(float*)(wsb+OFF_MT);
  float* vt   =(float*)(wsb+OFF_VT);

  hipMemsetAsync(wsb+OFF_GRAM, 0, 65536+1024, stream);   // G + srow (atomic targets)

  k1_proj <<<448,256,0,stream>>>(x, hw_th_w,hw_th_b, hw_ph_w,hw_ph_b, hw_g_w,hw_g_b,
                                 t_th_w,t_th_b, t_ph_w,t_ph_b,
                                 th_hw,ph_hw,g_hw,th_t,ph_t);
  k3_gram <<<256,256,0,stream>>>(x,G,srow);
  k4_prep <<<4,  256,0,stream>>>(G,srow, c_th_w,c_th_b,c_ph_w,c_ph_b,c_g_w,c_g_b,c_z_w,c_z_b,
                                 t_g_w,t_g_b,t_z_w,t_z_b, Mc,vc,Mt,vt);
  k5_tlogit<<<196,256,0,stream>>>(th_t,ph_t,Lt);
  k2_attn <<<256,256,0,stream>>>(th_hw,ph_hw,g_hw,y_hw);
  k6_final<<<448,256,0,stream>>>(x,y_hw,Lt,Mc,vc,Mt,vt,hw_z_w,hw_z_b,(float*)d_out);
}

// Round 6
// 665.854 us; speedup vs baseline: 3.8360x; 3.8360x over previous
//
#include <hip/hip_runtime.h>
#include <hip/hip_bf16.h>

typedef unsigned short u16;
typedef __attribute__((ext_vector_type(8))) short s16x8;
typedef __attribute__((ext_vector_type(4))) float f32x4;

#define B_    4
#define T_    7
#define C_    64
#define C2_   32
#define HW_   4096
#define KF_   224            // C2_*T_
#define NTOT_ 28672          // T_*HW_

// ---------------- bf16 helpers ----------------------------------------------
__device__ __forceinline__ float bf2f(u16 v){ return __uint_as_float(((unsigned)v)<<16); }
__device__ __forceinline__ u16 f2bf(float f){
  unsigned u = __float_as_uint(f);
  u = u + 0x7fffu + ((u>>16)&1u);   // round-to-nearest-even
  return (u16)(u>>16);
}

// ---------------- workspace layout (bytes) ----------------------------------
static const size_t OFF_TH_HW=0;                 // bf16 TOKEN-major [B][HW][KF]
static const size_t OFF_PH_HW=7340032;           // bf16 TOKEN-major [B][HW][KF]
static const size_t OFF_G_HW =14680064;          // bf16 k-major [B][KF][HW]
static const size_t OFF_Y_HW =22020096;          // bf16 k-major [B][KF][HW]
static const size_t OFF_TH_T =29360128;          // f32  [B][224][4096]
static const size_t OFF_PH_T =44040192;          // f32
static const size_t OFF_GRAM =58720256;          // f32 [B][64][64]  (atomics)
static const size_t OFF_SROW =58785792;          // f32 [B][64]      (atomics)
static const size_t OFF_LT   =58786816;          // f32 [B][7][7]
static const size_t OFF_MC   =58787840;          // f32 [B][64][64]
static const size_t OFF_VC   =58853376;          // f32 [B][64]
static const size_t OFF_MT   =58854400;          // f32 [64][64]
static const size_t OFF_VT   =58870784;          // f32 [64]

// ============================================================================
// K1: 5 channel-mix projections per (b,t,hw) location (f32 in).
//     proj 0,1 = hw theta/phi -> bf16 TOKEN-major [B][HW][KF] (kf = c2*T+t)
//     proj 2   = hw g         -> bf16 k-major [B][KF][HW]
//     proj 3,4 = t theta/phi  -> f32 k-major (precision for T-softmax)
// ============================================================================
__global__ __launch_bounds__(256) void k1_proj(
    const float* __restrict__ x,
    const float* w0,const float* bb0,const float* w1,const float* bb1,
    const float* w2,const float* bb2,const float* w3,const float* bb3,
    const float* w4,const float* bb4,
    u16* o0,u16* o1,u16* o2,float* o3,float* o4)
{
  __shared__ float wsm[5][C2_][C_];
  __shared__ float bsm[5][C2_];
  const float* wp[5]={w0,w1,w2,w3,w4};
  const float* bp[5]={bb0,bb1,bb2,bb3,bb4};
  int tid=threadIdx.x;
  for(int e=tid;e<5*C2_*C_;e+=256){ int pr=e>>11; int rc=e&2047; wsm[pr][rc>>6][rc&63]=wp[pr][rc]; }
  if(tid<5*C2_) bsm[tid>>5][tid&31]=bp[tid>>5][tid&31];
  __syncthreads();
  int bi=blockIdx.x;
  int b=bi/112, r=bi%112, t=r>>4;
  int p=((r&15)<<8)+tid;
  const float* xp = x + (((long)(b*T_+t))*C_)*HW_ + p;
  float xc[C_];
  #pragma unroll
  for(int c=0;c<C_;c++) xc[c]=xp[(long)c*HW_];
  long okm  = ((long)b*KF_ + t)*HW_ + p;          // k-major base (+c2*T*HW)
  long otok = ((long)(b*HW_) + p)*KF_ + t;        // token-major base (+c2*T)

  for(int pr=0;pr<5;pr++){
    for(int c2=0;c2<C2_;c2++){
      float acc=bsm[pr][c2];
      const float4* wr=(const float4*)wsm[pr][c2];
      #pragma unroll
      for(int q=0;q<16;q++){ float4 w4=wr[q];
        acc+=w4.x*xc[q*4]+w4.y*xc[q*4+1]+w4.z*xc[q*4+2]+w4.w*xc[q*4+3]; }
      if(pr==0)      o0[otok + c2*T_]=f2bf(acc);
      else if(pr==1) o1[otok + c2*T_]=f2bf(acc);
      else if(pr==2) o2[okm + (long)(c2*T_)*HW_]=f2bf(acc);
      else if(pr==3) o3[okm + (long)(c2*T_)*HW_]=acc;
      else           o4[okm + (long)(c2*T_)*HW_]=acc;
    }
  }
}

// ============================================================================
// K2: HW attention via MFMA (bf16 in/out).
//   Block = 64 queries of batch b; 4 waves x 16 queries; stream 64-key tiles.
//   S^T tile via mfma(A=phi, B=theta): D row=key, col=query -> P is directly
//   the PV A-fragment (zero lane-crossing). PV: B = g (k-major LDS).
//   No max-tracking (|logit| < ~20, f32-safe; verified round 2).
// ============================================================================
__global__ __launch_bounds__(256,2) void k2_attn(
    const u16* __restrict__ th_tok,  // [B][HW][KF]
    const u16* __restrict__ ph_tok,  // [B][HW][KF]
    const u16* __restrict__ g_km,    // [B][KF][HW]
    u16* __restrict__ y_g)           // [B][KF][HW]
{
  __shared__ __align__(16) u16 ph_s[64][228];   // [key][kf], pad->conflict-free
  __shared__ __align__(16) u16 g_s[224][68];    // [kf][key]
  __shared__ float den_s[64];
  int tid=threadIdx.x;
  int id=blockIdx.x;
  int b=(id&7)>>1;                      // XCD-pair swizzle: same b -> same XCDs
  int n=((id>>3)<<1)|(id&1);
  int p0=n<<6;
  int lane=tid&63, wv=tid>>6;
  int qw=wv<<4;                         // wave's query offset within block
  int m=lane&15, gq=lane>>4;

  // ---- preload theta B-fragments (7 k-steps of 32) for wave's 16 queries ----
  s16x8 thB[7];
  {
    const u16* thp = th_tok + ((long)(b*HW_ + p0 + qw + m))*KF_ + 4*gq;
    #pragma unroll
    for(int st=0; st<7; st++){
      union { s16x8 v; uint2 d[2]; } u;
      u.d[0]=*(const uint2*)(thp + st*32);
      u.d[1]=*(const uint2*)(thp + st*32 + 16);
      thB[st]=u.v;
    }
  }

  f32x4 Yacc[14];
  #pragma unroll
  for(int ft=0;ft<14;ft++) Yacc[ft]=(f32x4){0.f,0.f,0.f,0.f};
  float denp=0.f;

  const u16* phb = ph_tok + ((long)(b*HW_))*KF_;
  const u16* gb  = g_km  + ((long)(b*KF_))*HW_;

  // staging assignment
  int prow=tid>>2, pc0=(tid&3)*56;              // phi: 64 rows x 224, 4 thr/row
  int gro=tid>>3,  gc0=(tid&7)*8;               // g: rows it*32+gro, 8 thr/row
  uint4 rph[7], rg[7];

  // ---- prologue: load tile 0 ----
  #pragma unroll
  for(int q=0;q<7;q++) rph[q]=*(const uint4*)(phb + (long)prow*KF_ + pc0 + q*8);
  #pragma unroll
  for(int it=0;it<7;it++) rg[it]=*(const uint4*)(gb + (long)(it*32+gro)*HW_ + gc0);

  for(int tile=0; tile<64; tile++){
    __syncthreads();                    // prev tile's LDS reads done
    // ---- write staged regs to LDS (b64: rows not 16B-aligned) ----
    { u16* dst=&ph_s[prow][pc0];
      #pragma unroll
      for(int q=0;q<7;q++){
        *(uint2*)(dst+q*8)  =make_uint2(rph[q].x,rph[q].y);
        *(uint2*)(dst+q*8+4)=make_uint2(rph[q].z,rph[q].w);
      } }
    { 
      #pragma unroll
      for(int it=0;it<7;it++){
        u16* dst=&g_s[it*32+gro][gc0];
        *(uint2*)(dst)  =make_uint2(rg[it].x,rg[it].y);
        *(uint2*)(dst+4)=make_uint2(rg[it].z,rg[it].w);
      } }
    // ---- issue next tile's global loads (hide under compute) ----
    if(tile<63){
      int j1=(tile+1)<<6;
      #pragma unroll
      for(int q=0;q<7;q++) rph[q]=*(const uint4*)(phb + (long)(j1+prow)*KF_ + pc0 + q*8);
      #pragma unroll
      for(int it=0;it<7;it++) rg[it]=*(const uint4*)(gb + (long)(it*32+gro)*HW_ + j1 + gc0);
    }
    __syncthreads();                    // LDS tile visible

    // ---- S^T = Phi^T . Theta  (D: row=key 4*gq+r (+16*kt), col=query m) ----
    f32x4 Dt[4];
    #pragma unroll
    for(int kt=0;kt<4;kt++) Dt[kt]=(f32x4){0.f,0.f,0.f,0.f};
    #pragma unroll
    for(int st=0; st<7; st++){
      #pragma unroll
      for(int kt=0; kt<4; kt++){
        const u16* ap=&ph_s[kt*16+m][st*32+4*gq];
        union { s16x8 v; uint2 d[2]; } ua;
        ua.d[0]=*(const uint2*)ap;
        ua.d[1]=*(const uint2*)(ap+16);
        Dt[kt]=__builtin_amdgcn_mfma_f32_16x16x32_bf16(ua.v, thB[st], Dt[kt], 0,0,0);
      }
    }
    // ---- P = exp(S), denominator, pack PV A-fragments ----
    #pragma unroll
    for(int kt=0;kt<4;kt++){
      #pragma unroll
      for(int r=0;r<4;r++){ float pe=__expf(Dt[kt][r]); Dt[kt][r]=pe; denp+=pe; }
    }
    union { s16x8 v; u16 e[8]; } pa01, pa23;
    #pragma unroll
    for(int r=0;r<4;r++){
      pa01.e[r]=f2bf(Dt[0][r]); pa01.e[r+4]=f2bf(Dt[1][r]);
      pa23.e[r]=f2bf(Dt[2][r]); pa23.e[r+4]=f2bf(Dt[3][r]);
    }
    // ---- PV: Y[query][feat] += P . g  (B: col=feat m, k=key 4*gq+i) ----
    #pragma unroll
    for(int ft=0; ft<14; ft++){
      const u16* gp=&g_s[ft*16+m][4*gq];
      union { s16x8 v; uint2 d[2]; } b0,b1;
      b0.d[0]=*(const uint2*)gp;      b0.d[1]=*(const uint2*)(gp+16);
      b1.d[0]=*(const uint2*)(gp+32); b1.d[1]=*(const uint2*)(gp+48);
      Yacc[ft]=__builtin_amdgcn_mfma_f32_16x16x32_bf16(pa01.v, b0.v, Yacc[ft], 0,0,0);
      Yacc[ft]=__builtin_amdgcn_mfma_f32_16x16x32_bf16(pa23.v, b1.v, Yacc[ft], 0,0,0);
    }
  }

  // ---- denominator: reduce across gq groups (same query m) ----
  denp += __shfl_xor(denp, 16, 64);
  denp += __shfl_xor(denp, 32, 64);
  if(gq==0) den_s[qw+m]=denp;
  __syncthreads();
  float inv[4];
  #pragma unroll
  for(int r=0;r<4;r++) inv[r]=1.f/den_s[qw+4*gq+r];
  // ---- store Y (k-major out): query = p0+qw+4*gq+r, feat = 16*ft+m ----
  u16* yb = y_g + ((long)(b*KF_))*HW_ + p0 + qw + 4*gq;
  #pragma unroll
  for(int ft=0; ft<14; ft++){
    long fo=(long)(ft*16+m)*HW_;
    #pragma unroll
    for(int r=0;r<4;r++) yb[fo+r]=f2bf(Yacc[ft][r]*inv[r]);
  }
}

// ============================================================================
// K3: per-batch Gram G = X X^T (64x64) + row sums s = X 1  (f32 in)
// ============================================================================
__global__ __launch_bounds__(256) void k3_gram(const float* __restrict__ x,
                                               float* __restrict__ G, float* __restrict__ srow)
{
  __shared__ __align__(8) float xt[C_][68];
  int tid=threadIdx.x;
  int b=blockIdx.x>>6, ch=blockIdx.x&63;
  int ci0=(tid>>4)*4, cj0=(tid&15)*4;
  float acc[4][4];
  #pragma unroll
  for(int di=0;di<4;di++){acc[di][0]=0;acc[di][1]=0;acc[di][2]=0;acc[di][3]=0;}
  float sp=0.f;
  for(int st=0; st<7; st++){
    int n0=ch*448+st*64;
    int t=n0>>12, hw0=n0&4095;
    __syncthreads();
    for(int e=tid;e<C_*32;e+=256){ int c=e>>5, nn=e&31;
      *(float2*)&xt[c][nn*2]=*(const float2*)&x[(((long)(b*T_+t))*C_+c)*HW_+hw0+nn*2]; }
    __syncthreads();
    if(tid<C_){
      float s=0.f;
      for(int n=0;n<64;n++) s+=xt[tid][n];
      sp+=s;
    }
    for(int n=0;n<64;n++){
      float av[4],bv[4];
      #pragma unroll
      for(int d=0;d<4;d++){ av[d]=xt[ci0+d][n]; bv[d]=xt[cj0+d][n]; }
      #pragma unroll
      for(int di=0;di<4;di++)
        #pragma unroll
        for(int dj=0;dj<4;dj++)
          acc[di][dj]+=av[di]*bv[dj];
    }
  }
  float* Gb=G+b*4096;
  #pragma unroll
  for(int di=0;di<4;di++)
    #pragma unroll
    for(int dj=0;dj<4;dj++)
      atomicAdd(&Gb[(ci0+di)*64+cj0+dj], acc[di][dj]);
  if(tid<C_) atomicAdd(&srow[b*64+tid], sp);
}

// ============================================================================
// K4: per-batch C-branch collapse: Mc = Wz softmax(Wth G Wph^T + bias) Wg, vc.
//     Block 0 also builds T-branch Mt = Wz_t Wg_t, vt.
// ============================================================================
__global__ __launch_bounds__(256) void k4_prep(
  const float* __restrict__ G, const float* __restrict__ srow,
  const float* cthw,const float* cthb,const float* cphw,const float* cphb,
  const float* cgw,const float* cgb,const float* czw,const float* czb,
  const float* tgw,const float* tgb,const float* tzw,const float* tzb,
  float* Mc, float* vc, float* Mt, float* vt)
{
  __shared__ float Gl[64][65];
  __shared__ float A1[32][65];
  __shared__ float fl[32][33];
  __shared__ float B1[32][65];
  __shared__ float sv[64], uu[32], vv[32], fb[32];
  int tid=threadIdx.x, b=blockIdx.x;
  for(int e=tid;e<4096;e+=256) Gl[e>>6][e&63]=G[b*4096+e];
  if(tid<64) sv[tid]=srow[b*64+tid];
  __syncthreads();
  if(tid<32){
    float a=0,bp=0;
    for(int c=0;c<64;c++){ a+=cthw[tid*64+c]*sv[c]; bp+=cphw[tid*64+c]*sv[c]; }
    uu[tid]=a; vv[tid]=bp;
  }
  __syncthreads();
  for(int e=tid;e<2048;e+=256){ int i=e>>6,cp=e&63;
    float a=0;
    for(int c=0;c<64;c++) a+=cthw[i*64+c]*Gl[c][cp];
    A1[i][cp]=a;
  }
  __syncthreads();
  for(int e=tid;e<1024;e+=256){ int i=e>>5,j=e&31;
    float a=0;
    for(int cp=0;cp<64;cp++) a+=A1[i][cp]*cphw[j*64+cp];
    a+=uu[i]*cphb[j]+cthb[i]*vv[j]+(float)NTOT_*cthb[i]*cphb[j];
    fl[i][j]=a;
  }
  __syncthreads();
  if(tid<32){
    float mx=-1e30f;
    for(int j=0;j<32;j++) mx=fmaxf(mx,fl[tid][j]);
    float s=0;
    for(int j=0;j<32;j++){ float e2=__expf(fl[tid][j]-mx); fl[tid][j]=e2; s+=e2; }
    float invs=1.f/s;
    for(int j=0;j<32;j++) fl[tid][j]*=invs;
    float a=0;
    for(int j=0;j<32;j++) a+=fl[tid][j]*cgb[j];
    fb[tid]=a;
  }
  __syncthreads();
  for(int e=tid;e<2048;e+=256){ int i=e>>6,cp=e&63;
    float a=0;
    for(int j=0;j<32;j++) a+=fl[i][j]*cgw[j*64+cp];
    B1[i][cp]=a;
  }
  __syncthreads();
  for(int e=tid;e<4096;e+=256){ int c=e>>6,cp=e&63;
    float a=0;
    for(int i=0;i<32;i++) a+=czw[c*32+i]*B1[i][cp];
    Mc[b*4096+e]=a;
  }
  if(tid<64){
    float a=0;
    for(int i=0;i<32;i++) a+=czw[tid*32+i]*fb[i];
    vc[b*64+tid]=a+czb[tid];
  }
  if(b==0){
    for(int e=tid;e<4096;e+=256){ int c=e>>6,cp=e&63;
      float a=0;
      for(int i=0;i<32;i++) a+=tzw[c*32+i]*tgw[i*64+cp];
      Mt[e]=a;
    }
    if(tid<64){
      float a=0;
      for(int i=0;i<32;i++) a+=tzw[tid*32+i]*tgb[i];
      vt[tid]=a+tzb[tid];
    }
  }
}

// ============================================================================
// K5: T-branch raw logits L[b][t][s] = sum_{c2,hw} th_t . ph_t   (f32)
// ============================================================================
__global__ __launch_bounds__(256) void k5_tlogit(const float* __restrict__ th,
                                                 const float* __restrict__ ph,
                                                 float* __restrict__ Lt)
{
  __shared__ float wsum[4];
  int tid=threadIdx.x;
  int bi=blockIdx.x;
  int b=bi/49, r=bi%49, t=r/7, s=r%7;
  const float* A =th+((long)b*C2_*T_+t)*HW_;
  const float* Bp=ph+((long)b*C2_*T_+s)*HW_;
  float part=0.f;
  for(int c2=0;c2<C2_;c2++){
    const float4* a4=(const float4*)(A +(long)c2*T_*HW_);
    const float4* b4=(const float4*)(Bp+(long)c2*T_*HW_);
    #pragma unroll
    for(int rr=0;rr<4;rr++){
      int idx=rr*256+tid;
      float4 av=a4[idx], bv=b4[idx];
      part+=av.x*bv.x+av.y*bv.y+av.z*bv.z+av.w*bv.w;
    }
  }
  for(int off=32;off>0;off>>=1) part+=__shfl_down(part,off,64);
  if((tid&63)==0) wsum[tid>>6]=part;
  __syncthreads();
  if(tid==0) Lt[bi]=wsum[0]+wsum[1]+wsum[2]+wsum[3];
}

// ============================================================================
// K6: fused epilogue per (b,t,hw):
//   out = x + Wz_hw . y_hw + Mc . xcol + Mt . xbar + const
// ============================================================================
__global__ __launch_bounds__(256) void k6_final(
  const float* __restrict__ x, const u16* __restrict__ y_hw,
  const float* __restrict__ Lt, const float* __restrict__ Mc, const float* __restrict__ vc,
  const float* __restrict__ Mt, const float* __restrict__ vt,
  const float* hzw, const float* hzb, float* __restrict__ out)
{
  __shared__ float Mcl[64][64];
  __shared__ float Mtl[64][64];
  __shared__ float Wzl[64][32];
  __shared__ float cst[64];
  __shared__ float ftr[8];
  __shared__ float raw[8];
  int tid=threadIdx.x;
  int bi=blockIdx.x;
  int b=bi/112, r=bi%112, t=r>>4;
  int p=((r&15)<<8)+tid;
  for(int e=tid;e<4096;e+=256){ Mcl[e>>6][e&63]=Mc[b*4096+e]; Mtl[e>>6][e&63]=Mt[e]; }
  for(int e=tid;e<2048;e+=256) Wzl[e>>5][e&31]=hzw[e];
  if(tid<64) cst[tid]=vc[b*64+tid]+vt[tid]+hzb[tid];
  if(tid<7) raw[tid]=Lt[b*49+t*7+tid];
  __syncthreads();
  if(tid==0){
    float mx=-1e30f;
    for(int s=0;s<7;s++) mx=fmaxf(mx,raw[s]);
    float ssum=0.f; float e7[7];
    #pragma unroll
    for(int s=0;s<7;s++){ e7[s]=__expf(raw[s]-mx); ssum+=e7[s]; }
    #pragma unroll
    for(int s=0;s<7;s++) ftr[s]=e7[s]/ssum;
  }
  __syncthreads();
  float xcol[64], xbar[64];
  #pragma unroll
  for(int c=0;c<64;c++) xbar[c]=0.f;
  for(int s=0;s<7;s++){
    float fs=ftr[s];
    const float* xp=x+(((long)(b*T_+s))*C_)*HW_+p;
    if(s==t){
      #pragma unroll
      for(int c=0;c<64;c++){ float v0=xp[(long)c*HW_]; xcol[c]=v0; xbar[c]+=fs*v0; }
    } else {
      #pragma unroll
      for(int c=0;c<64;c++){ float v0=xp[(long)c*HW_]; xbar[c]+=fs*v0; }
    }
  }
  float yv[32];
  const u16* yp=y_hw+((long)b*KF_+t)*HW_+p;
  #pragma unroll
  for(int c2=0;c2<32;c2++) yv[c2]=bf2f(yp[(long)(c2*T_)*HW_]);
  float* op=out+(((long)(b*T_+t))*C_)*HW_+p;
  #pragma unroll
  for(int c=0;c<64;c++){
    float a=xcol[c]+cst[c];
    const float4* wr=(const float4*)Wzl[c];
    #pragma unroll
    for(int q=0;q<8;q++){ float4 w4=wr[q];
      a+=w4.x*yv[q*4]+w4.y*yv[q*4+1]+w4.z*yv[q*4+2]+w4.w*yv[q*4+3]; }
    const float4* mr=(const float4*)Mcl[c];
    const float4* tr=(const float4*)Mtl[c];
    #pragma unroll
    for(int q=0;q<16;q++){
      float4 m4=mr[q], t4=tr[q];
      a+=m4.x*xcol[q*4]+m4.y*xcol[q*4+1]+m4.z*xcol[q*4+2]+m4.w*xcol[q*4+3];
      a+=t4.x*xbar[q*4]+t4.y*xbar[q*4+1]+t4.z*xbar[q*4+2]+t4.w*xbar[q*4+3];
    }
    op[(long)c*HW_]=a;
  }
}

// ============================================================================
extern "C" void kernel_launch(void* const* d_in, const int* in_sizes, int n_in,
                              void* d_out, int out_size, void* d_ws, size_t ws_size,
                              hipStream_t stream)
{
  (void)in_sizes; (void)n_in; (void)out_size; (void)ws_size;
  const float* x      =(const float*)d_in[0];
  const float* hw_th_w=(const float*)d_in[1];  const float* hw_th_b=(const float*)d_in[2];
  const float* hw_ph_w=(const float*)d_in[3];  const float* hw_ph_b=(const float*)d_in[4];
  const float* hw_g_w =(const float*)d_in[5];  const float* hw_g_b =(const float*)d_in[6];
  const float* hw_z_w =(const float*)d_in[7];  const float* hw_z_b =(const float*)d_in[8];
  const float* c_th_w =(const float*)d_in[9];  const float* c_th_b =(const float*)d_in[10];
  const float* c_ph_w =(const float*)d_in[11]; const float* c_ph_b =(const float*)d_in[12];
  const float* c_g_w  =(const float*)d_in[13]; const float* c_g_b  =(const float*)d_in[14];
  const float* c_z_w  =(const float*)d_in[15]; const float* c_z_b  =(const float*)d_in[16];
  const float* t_th_w =(const float*)d_in[17]; const float* t_th_b =(const float*)d_in[18];
  const float* t_ph_w =(const float*)d_in[19]; const float* t_ph_b =(const float*)d_in[20];
  const float* t_g_w  =(const float*)d_in[21]; const float* t_g_b  =(const float*)d_in[22];
  const float* t_z_w  =(const float*)d_in[23]; const float* t_z_b  =(const float*)d_in[24];

  char* wsb=(char*)d_ws;
  u16*   th_hw=(u16*)  (wsb+OFF_TH_HW);
  u16*   ph_hw=(u16*)  (wsb+OFF_PH_HW);
  u16*   g_hw =(u16*)  (wsb+OFF_G_HW);
  u16*   y_hw =(u16*)  (wsb+OFF_Y_HW);
  float* th_t =(float*)(wsb+OFF_TH_T);
  float* ph_t =(float*)(wsb+OFF_PH_T);
  float* G    =(float*)(wsb+OFF_GRAM);
  float* srow =(float*)(wsb+OFF_SROW);
  float* Lt   =(float*)(wsb+OFF_LT);
  float* Mc   =(float*)(wsb+OFF_MC);
  float* vc   =(float*)(wsb+OFF_VC);
  float* Mt   =(float*)(wsb+OFF_MT);
  float* vt   =(float*)(wsb+OFF_VT);

  hipMemsetAsync(wsb+OFF_GRAM, 0, 65536+1024, stream);   // G + srow (atomic targets)

  k1_proj <<<448,256,0,stream>>>(x, hw_th_w,hw_th_b, hw_ph_w,hw_ph_b, hw_g_w,hw_g_b,
                                 t_th_w,t_th_b, t_ph_w,t_ph_b,
                                 th_hw,ph_hw,g_hw,th_t,ph_t);
  k3_gram <<<256,256,0,stream>>>(x,G,srow);
  k4_prep <<<4,  256,0,stream>>>(G,srow, c_th_w,c_th_b,c_ph_w,c_ph_b,c_g_w,c_g_b,c_z_w,c_z_b,
                                 t_g_w,t_g_b,t_z_w,t_z_b, Mc,vc,Mt,vt);
  k5_tlogit<<<196,256,0,stream>>>(th_t,ph_t,Lt);
  k2_attn <<<256,256,0,stream>>>(th_hw,ph_hw,g_hw,y_hw);
  k6_final<<<448,256,0,stream>>>(x,y_hw,Lt,Mc,vc,Mt,vt,hw_z_w,hw_z_b,(float*)d_out);
}

// Round 7
// 624.041 us; speedup vs baseline: 4.0930x; 1.0670x over previous
//
#include <hip/hip_runtime.h>
#include <hip/hip_bf16.h>

typedef unsigned short u16;
typedef __attribute__((ext_vector_type(8))) short s16x8;
typedef __attribute__((ext_vector_type(4))) float f32x4;

#define B_    4
#define T_    7
#define C_    64
#define C2_   32
#define HW_   4096
#define KF_   224            // C2_*T_
#define NTOT_ 28672          // T_*HW_

// ---------------- bf16 helpers ----------------------------------------------
__device__ __forceinline__ float bf2f(u16 v){ return __uint_as_float(((unsigned)v)<<16); }
__device__ __forceinline__ u16 f2bf(float f){
  unsigned u = __float_as_uint(f);
  u = u + 0x7fffu + ((u>>16)&1u);   // round-to-nearest-even
  return (u16)(u>>16);
}

// ---------------- workspace layout (bytes) ----------------------------------
static const size_t OFF_TH_HW=0;                 // bf16 TOKEN-major [B][HW][KF] (kf = t*32+c2)
static const size_t OFF_PH_HW=7340032;           // bf16 TOKEN-major (same kf order)
static const size_t OFF_G_HW =14680064;          // bf16 k-major [B][KF][HW] (kf = c2*T+t)
static const size_t OFF_Y_HW =22020096;          // bf16 k-major [B][KF][HW] (kf = c2*T+t)
static const size_t OFF_TH_T =29360128;          // f32  [B][224][4096]
static const size_t OFF_PH_T =44040192;          // f32
static const size_t OFF_GRAM =58720256;          // f32 [B][64][64]  (atomics)
static const size_t OFF_SROW =58785792;          // f32 [B][64]      (atomics)
static const size_t OFF_LT   =58786816;          // f32 [B][7][7]
static const size_t OFF_MC   =58787840;          // f32 [B][64][64]
static const size_t OFF_VC   =58853376;          // f32 [B][64]
static const size_t OFF_MT   =58854400;          // f32 [64][64]
static const size_t OFF_VT   =58870784;          // f32 [64]

// ============================================================================
// K1: 5 channel-mix projections per (b,t,hw) location (f32 in).
//     proj 0,1 = hw theta/phi -> bf16 TOKEN-major, kf = t*32+c2 (contiguous
//                per (t,pixel) -> 4x16B vector stores; permutation is shared
//                by theta & phi so the S dot product is unchanged)
//     proj 2   = hw g         -> bf16 k-major [B][KF][HW] (kf = c2*T+t)
//     proj 3,4 = t theta/phi  -> f32 k-major (precision for T-softmax)
// ============================================================================
__global__ __launch_bounds__(256) void k1_proj(
    const float* __restrict__ x,
    const float* w0,const float* bb0,const float* w1,const float* bb1,
    const float* w2,const float* bb2,const float* w3,const float* bb3,
    const float* w4,const float* bb4,
    u16* o0,u16* o1,u16* o2,float* o3,float* o4)
{
  __shared__ float wsm[5][C2_][C_];
  __shared__ float bsm[5][C2_];
  const float* wp[5]={w0,w1,w2,w3,w4};
  const float* bp[5]={bb0,bb1,bb2,bb3,bb4};
  int tid=threadIdx.x;
  for(int e=tid;e<5*C2_*C_;e+=256){ int pr=e>>11; int rc=e&2047; wsm[pr][rc>>6][rc&63]=wp[pr][rc]; }
  if(tid<5*C2_) bsm[tid>>5][tid&31]=bp[tid>>5][tid&31];
  __syncthreads();
  int bi=blockIdx.x;
  int b=bi/112, r=bi%112, t=r>>4;
  int p=((r&15)<<8)+tid;
  const float* xp = x + (((long)(b*T_+t))*C_)*HW_ + p;
  float xc[C_];
  #pragma unroll
  for(int c=0;c<C_;c++) xc[c]=xp[(long)c*HW_];
  long okm  = ((long)b*KF_ + t)*HW_ + p;          // k-major base (+c2*T*HW)
  long otok = ((long)(b*HW_) + p)*KF_ + t*C2_;    // token-major base (+c2)

  // ---- hw theta/phi: buffered, contiguous 64B stores per projection ----
  union { u16 e[32]; uint4 q[4]; } tbuf, pbuf;
  #pragma unroll
  for(int c2=0;c2<32;c2++){
    float a0=bsm[0][c2], a1=bsm[1][c2];
    const float4* w0r=(const float4*)wsm[0][c2];
    const float4* w1r=(const float4*)wsm[1][c2];
    #pragma unroll
    for(int q=0;q<16;q++){
      float4 wa=w0r[q], wb=w1r[q];
      a0+=wa.x*xc[q*4]+wa.y*xc[q*4+1]+wa.z*xc[q*4+2]+wa.w*xc[q*4+3];
      a1+=wb.x*xc[q*4]+wb.y*xc[q*4+1]+wb.z*xc[q*4+2]+wb.w*xc[q*4+3];
    }
    tbuf.e[c2]=f2bf(a0); pbuf.e[c2]=f2bf(a1);
  }
  {
    u16* t0=o0+otok; u16* p0p=o1+otok;   // 16B-aligned: (…*224 + t*32)*2
    #pragma unroll
    for(int q=0;q<4;q++){ *(uint4*)(t0+q*8)=tbuf.q[q]; *(uint4*)(p0p+q*8)=pbuf.q[q]; }
  }
  // ---- g (bf16 k-major) and t-branch theta/phi (f32 k-major) ----
  for(int pr=2;pr<5;pr++){
    for(int c2=0;c2<C2_;c2++){
      float acc=bsm[pr][c2];
      const float4* wr=(const float4*)wsm[pr][c2];
      #pragma unroll
      for(int q=0;q<16;q++){ float4 w4=wr[q];
        acc+=w4.x*xc[q*4]+w4.y*xc[q*4+1]+w4.z*xc[q*4+2]+w4.w*xc[q*4+3]; }
      long oa = okm + (long)(c2*T_)*HW_;
      if(pr==2)      o2[oa]=f2bf(acc);
      else if(pr==3) o3[oa]=acc;
      else           o4[oa]=acc;
    }
  }
}

// ============================================================================
// K2: HW attention via MFMA (bf16 in/out). Unchanged from round 6 (verified).
// ============================================================================
__global__ __launch_bounds__(256,2) void k2_attn(
    const u16* __restrict__ th_tok,  // [B][HW][KF]
    const u16* __restrict__ ph_tok,  // [B][HW][KF]
    const u16* __restrict__ g_km,    // [B][KF][HW]
    u16* __restrict__ y_g)           // [B][KF][HW]
{
  __shared__ __align__(16) u16 ph_s[64][228];   // [key][kf], pad->conflict-free
  __shared__ __align__(16) u16 g_s[224][68];    // [kf][key]
  __shared__ float den_s[64];
  int tid=threadIdx.x;
  int id=blockIdx.x;
  int b=(id&7)>>1;                      // XCD-pair swizzle: same b -> same XCDs
  int n=((id>>3)<<1)|(id&1);
  int p0=n<<6;
  int lane=tid&63, wv=tid>>6;
  int qw=wv<<4;                         // wave's query offset within block
  int m=lane&15, gq=lane>>4;

  // ---- preload theta B-fragments (7 k-steps of 32) for wave's 16 queries ----
  s16x8 thB[7];
  {
    const u16* thp = th_tok + ((long)(b*HW_ + p0 + qw + m))*KF_ + 4*gq;
    #pragma unroll
    for(int st=0; st<7; st++){
      union { s16x8 v; uint2 d[2]; } u;
      u.d[0]=*(const uint2*)(thp + st*32);
      u.d[1]=*(const uint2*)(thp + st*32 + 16);
      thB[st]=u.v;
    }
  }

  f32x4 Yacc[14];
  #pragma unroll
  for(int ft=0;ft<14;ft++) Yacc[ft]=(f32x4){0.f,0.f,0.f,0.f};
  float denp=0.f;

  const u16* phb = ph_tok + ((long)(b*HW_))*KF_;
  const u16* gb  = g_km  + ((long)(b*KF_))*HW_;

  // staging assignment
  int prow=tid>>2, pc0=(tid&3)*56;              // phi: 64 rows x 224, 4 thr/row
  int gro=tid>>3,  gc0=(tid&7)*8;               // g: rows it*32+gro, 8 thr/row
  uint4 rph[7], rg[7];

  // ---- prologue: load tile 0 ----
  #pragma unroll
  for(int q=0;q<7;q++) rph[q]=*(const uint4*)(phb + (long)prow*KF_ + pc0 + q*8);
  #pragma unroll
  for(int it=0;it<7;it++) rg[it]=*(const uint4*)(gb + (long)(it*32+gro)*HW_ + gc0);

  for(int tile=0; tile<64; tile++){
    __syncthreads();                    // prev tile's LDS reads done
    { u16* dst=&ph_s[prow][pc0];
      #pragma unroll
      for(int q=0;q<7;q++){
        *(uint2*)(dst+q*8)  =make_uint2(rph[q].x,rph[q].y);
        *(uint2*)(dst+q*8+4)=make_uint2(rph[q].z,rph[q].w);
      } }
    {
      #pragma unroll
      for(int it=0;it<7;it++){
        u16* dst=&g_s[it*32+gro][gc0];
        *(uint2*)(dst)  =make_uint2(rg[it].x,rg[it].y);
        *(uint2*)(dst+4)=make_uint2(rg[it].z,rg[it].w);
      } }
    if(tile<63){
      int j1=(tile+1)<<6;
      #pragma unroll
      for(int q=0;q<7;q++) rph[q]=*(const uint4*)(phb + (long)(j1+prow)*KF_ + pc0 + q*8);
      #pragma unroll
      for(int it=0;it<7;it++) rg[it]=*(const uint4*)(gb + (long)(it*32+gro)*HW_ + j1 + gc0);
    }
    __syncthreads();                    // LDS tile visible

    // ---- S^T = Phi^T . Theta ----
    f32x4 Dt[4];
    #pragma unroll
    for(int kt=0;kt<4;kt++) Dt[kt]=(f32x4){0.f,0.f,0.f,0.f};
    #pragma unroll
    for(int st=0; st<7; st++){
      #pragma unroll
      for(int kt=0; kt<4; kt++){
        const u16* ap=&ph_s[kt*16+m][st*32+4*gq];
        union { s16x8 v; uint2 d[2]; } ua;
        ua.d[0]=*(const uint2*)ap;
        ua.d[1]=*(const uint2*)(ap+16);
        Dt[kt]=__builtin_amdgcn_mfma_f32_16x16x32_bf16(ua.v, thB[st], Dt[kt], 0,0,0);
      }
    }
    // ---- P = exp(S), denominator, pack PV A-fragments ----
    #pragma unroll
    for(int kt=0;kt<4;kt++){
      #pragma unroll
      for(int r=0;r<4;r++){ float pe=__expf(Dt[kt][r]); Dt[kt][r]=pe; denp+=pe; }
    }
    union { s16x8 v; u16 e[8]; } pa01, pa23;
    #pragma unroll
    for(int r=0;r<4;r++){
      pa01.e[r]=f2bf(Dt[0][r]); pa01.e[r+4]=f2bf(Dt[1][r]);
      pa23.e[r]=f2bf(Dt[2][r]); pa23.e[r+4]=f2bf(Dt[3][r]);
    }
    // ---- PV ----
    #pragma unroll
    for(int ft=0; ft<14; ft++){
      const u16* gp=&g_s[ft*16+m][4*gq];
      union { s16x8 v; uint2 d[2]; } b0,b1;
      b0.d[0]=*(const uint2*)gp;      b0.d[1]=*(const uint2*)(gp+16);
      b1.d[0]=*(const uint2*)(gp+32); b1.d[1]=*(const uint2*)(gp+48);
      Yacc[ft]=__builtin_amdgcn_mfma_f32_16x16x32_bf16(pa01.v, b0.v, Yacc[ft], 0,0,0);
      Yacc[ft]=__builtin_amdgcn_mfma_f32_16x16x32_bf16(pa23.v, b1.v, Yacc[ft], 0,0,0);
    }
  }

  denp += __shfl_xor(denp, 16, 64);
  denp += __shfl_xor(denp, 32, 64);
  if(gq==0) den_s[qw+m]=denp;
  __syncthreads();
  float inv[4];
  #pragma unroll
  for(int r=0;r<4;r++) inv[r]=1.f/den_s[qw+4*gq+r];
  u16* yb = y_g + ((long)(b*KF_))*HW_ + p0 + qw + 4*gq;
  #pragma unroll
  for(int ft=0; ft<14; ft++){
    long fo=(long)(ft*16+m)*HW_;
    #pragma unroll
    for(int r=0;r<4;r++) yb[fo+r]=f2bf(Yacc[ft][r]*inv[r]);
  }
}

// ============================================================================
// K3: per-batch Gram G = X X^T (64x64) + row sums s = X 1  (f32 in)
// ============================================================================
__global__ __launch_bounds__(256) void k3_gram(const float* __restrict__ x,
                                               float* __restrict__ G, float* __restrict__ srow)
{
  __shared__ __align__(8) float xt[C_][68];
  int tid=threadIdx.x;
  int b=blockIdx.x>>6, ch=blockIdx.x&63;
  int ci0=(tid>>4)*4, cj0=(tid&15)*4;
  float acc[4][4];
  #pragma unroll
  for(int di=0;di<4;di++){acc[di][0]=0;acc[di][1]=0;acc[di][2]=0;acc[di][3]=0;}
  float sp=0.f;
  for(int st=0; st<7; st++){
    int n0=ch*448+st*64;
    int t=n0>>12, hw0=n0&4095;
    __syncthreads();
    for(int e=tid;e<C_*32;e+=256){ int c=e>>5, nn=e&31;
      *(float2*)&xt[c][nn*2]=*(const float2*)&x[(((long)(b*T_+t))*C_+c)*HW_+hw0+nn*2]; }
    __syncthreads();
    if(tid<C_){
      float s=0.f;
      for(int n=0;n<64;n++) s+=xt[tid][n];
      sp+=s;
    }
    for(int n=0;n<64;n++){
      float av[4],bv[4];
      #pragma unroll
      for(int d=0;d<4;d++){ av[d]=xt[ci0+d][n]; bv[d]=xt[cj0+d][n]; }
      #pragma unroll
      for(int di=0;di<4;di++)
        #pragma unroll
        for(int dj=0;dj<4;dj++)
          acc[di][dj]+=av[di]*bv[dj];
    }
  }
  float* Gb=G+b*4096;
  #pragma unroll
  for(int di=0;di<4;di++)
    #pragma unroll
    for(int dj=0;dj<4;dj++)
      atomicAdd(&Gb[(ci0+di)*64+cj0+dj], acc[di][dj]);
  if(tid<C_) atomicAdd(&srow[b*64+tid], sp);
}

// ============================================================================
// K4: per-batch C-branch collapse: Mc = Wz softmax(Wth G Wph^T + bias) Wg, vc.
//     Block 0 also builds T-branch Mt = Wz_t Wg_t, vt.
// ============================================================================
__global__ __launch_bounds__(256) void k4_prep(
  const float* __restrict__ G, const float* __restrict__ srow,
  const float* cthw,const float* cthb,const float* cphw,const float* cphb,
  const float* cgw,const float* cgb,const float* czw,const float* czb,
  const float* tgw,const float* tgb,const float* tzw,const float* tzb,
  float* Mc, float* vc, float* Mt, float* vt)
{
  __shared__ float Gl[64][65];
  __shared__ float A1[32][65];
  __shared__ float fl[32][33];
  __shared__ float B1[32][65];
  __shared__ float sv[64], uu[32], vv[32], fb[32];
  int tid=threadIdx.x, b=blockIdx.x;
  for(int e=tid;e<4096;e+=256) Gl[e>>6][e&63]=G[b*4096+e];
  if(tid<64) sv[tid]=srow[b*64+tid];
  __syncthreads();
  if(tid<32){
    float a=0,bp=0;
    for(int c=0;c<64;c++){ a+=cthw[tid*64+c]*sv[c]; bp+=cphw[tid*64+c]*sv[c]; }
    uu[tid]=a; vv[tid]=bp;
  }
  __syncthreads();
  for(int e=tid;e<2048;e+=256){ int i=e>>6,cp=e&63;
    float a=0;
    for(int c=0;c<64;c++) a+=cthw[i*64+c]*Gl[c][cp];
    A1[i][cp]=a;
  }
  __syncthreads();
  for(int e=tid;e<1024;e+=256){ int i=e>>5,j=e&31;
    float a=0;
    for(int cp=0;cp<64;cp++) a+=A1[i][cp]*cphw[j*64+cp];
    a+=uu[i]*cphb[j]+cthb[i]*vv[j]+(float)NTOT_*cthb[i]*cphb[j];
    fl[i][j]=a;
  }
  __syncthreads();
  if(tid<32){
    float mx=-1e30f;
    for(int j=0;j<32;j++) mx=fmaxf(mx,fl[tid][j]);
    float s=0;
    for(int j=0;j<32;j++){ float e2=__expf(fl[tid][j]-mx); fl[tid][j]=e2; s+=e2; }
    float invs=1.f/s;
    for(int j=0;j<32;j++) fl[tid][j]*=invs;
    float a=0;
    for(int j=0;j<32;j++) a+=fl[tid][j]*cgb[j];
    fb[tid]=a;
  }
  __syncthreads();
  for(int e=tid;e<2048;e+=256){ int i=e>>6,cp=e&63;
    float a=0;
    for(int j=0;j<32;j++) a+=fl[i][j]*cgw[j*64+cp];
    B1[i][cp]=a;
  }
  __syncthreads();
  for(int e=tid;e<4096;e+=256){ int c=e>>6,cp=e&63;
    float a=0;
    for(int i=0;i<32;i++) a+=czw[c*32+i]*B1[i][cp];
    Mc[b*4096+e]=a;
  }
  if(tid<64){
    float a=0;
    for(int i=0;i<32;i++) a+=czw[tid*32+i]*fb[i];
    vc[b*64+tid]=a+czb[tid];
  }
  if(b==0){
    for(int e=tid;e<4096;e+=256){ int c=e>>6,cp=e&63;
      float a=0;
      for(int i=0;i<32;i++) a+=tzw[c*32+i]*tgw[i*64+cp];
      Mt[e]=a;
    }
    if(tid<64){
      float a=0;
      for(int i=0;i<32;i++) a+=tzw[tid*32+i]*tgb[i];
      vt[tid]=a+tzb[tid];
    }
  }
}

// ============================================================================
// K5: T-branch raw logits L[b][t][s] = sum_{c2,hw} th_t . ph_t   (f32)
// ============================================================================
__global__ __launch_bounds__(256) void k5_tlogit(const float* __restrict__ th,
                                                 const float* __restrict__ ph,
                                                 float* __restrict__ Lt)
{
  __shared__ float wsum[4];
  int tid=threadIdx.x;
  int bi=blockIdx.x;
  int b=bi/49, r=bi%49, t=r/7, s=r%7;
  const float* A =th+((long)b*C2_*T_+t)*HW_;
  const float* Bp=ph+((long)b*C2_*T_+s)*HW_;
  float part=0.f;
  for(int c2=0;c2<C2_;c2++){
    const float4* a4=(const float4*)(A +(long)c2*T_*HW_);
    const float4* b4=(const float4*)(Bp+(long)c2*T_*HW_);
    #pragma unroll
    for(int rr=0;rr<4;rr++){
      int idx=rr*256+tid;
      float4 av=a4[idx], bv=b4[idx];
      part+=av.x*bv.x+av.y*bv.y+av.z*bv.z+av.w*bv.w;
    }
  }
  for(int off=32;off>0;off>>=1) part+=__shfl_down(part,off,64);
  if((tid&63)==0) wsum[tid>>6]=part;
  __syncthreads();
  if(tid==0) Lt[bi]=wsum[0]+wsum[1]+wsum[2]+wsum[3];
}

// ============================================================================
// K6 v2: t-fused MFMA epilogue.
//   Block = (b, 64-pixel chunk), all 7 t.  512 threads = 8 waves.
//   out[t][c][px] = M . V + cst[c] + x[t][c][px]
//     M = [Wz | Mc(b) | Mt]  64x160 bf16 (LDS, loaded once)
//     V = [y_t ; x_t ; xbar_t] 160 x 64px bf16 (LDS, rebuilt per t; stored
//         transposed [px][k] so B-fragments are contiguous b64 reads)
//   Same verified fragment convention as k2: D row = A-row, col = B-lane-m.
// ============================================================================
__global__ __launch_bounds__(512) void k6_final(
  const float* __restrict__ x, const u16* __restrict__ y_hw,
  const float* __restrict__ Lt, const float* __restrict__ Mc,
  const float* __restrict__ vc, const float* __restrict__ Mt,
  const float* __restrict__ vt, const float* __restrict__ hzw,
  const float* __restrict__ hzb, float* __restrict__ out)
{
  __shared__ u16 Msm[64][164];     // [out][k], pad 160->164 (no m/m+8 conflict)
  __shared__ u16 Vsm[64][164];     // [px][k]
  __shared__ float cst[64];
  __shared__ float fsm[7][8];
  int tid=threadIdx.x;
  int bi=blockIdx.x;
  int b=bi>>6;
  int hw0=(bi&63)<<6;
  // ---- load M (bf16) ----
  for(int e=tid;e<64*160;e+=512){
    int c=e/160, k=e-c*160;
    float v;
    if(k<32)       v=hzw[c*32+k];
    else if(k<96)  v=Mc[b*4096 + c*64 + (k-32)];
    else           v=Mt[c*64 + (k-96)];
    Msm[c][k]=f2bf(v);
  }
  if(tid<64) cst[tid]=vc[b*64+tid]+vt[tid]+hzb[tid];
  if(tid<7){
    float raw[7], mx=-1e30f;
    #pragma unroll
    for(int s=0;s<7;s++){ raw[s]=Lt[b*49+tid*7+s]; mx=fmaxf(mx,raw[s]); }
    float ss=0.f;
    #pragma unroll
    for(int s=0;s<7;s++){ raw[s]=__expf(raw[s]-mx); ss+=raw[s]; }
    float inv=1.f/ss;
    #pragma unroll
    for(int s=0;s<7;s++) fsm[tid][s]=raw[s]*inv;
  }
  int lane=tid&63, wv=tid>>6;
  int m=lane&15, gq=lane>>4;
  int pt=wv&3, oh=wv>>2;
  int px0=pt*16;
  int o0r=oh*32, o1r=oh*32+16;
  const float* xb = x + ((long)(b*T_))*C_*HW_ + hw0;
  const u16*  yb = y_hw + ((long)(b*KF_))*HW_ + hw0;
  float* ob = out + ((long)(b*T_))*C_*HW_ + hw0;
  __syncthreads();

  for(int t=0;t<7;t++){
    if(t) __syncthreads();           // prev GEMM done reading Vsm
    // ---- build V^T: rows = px, cols = k ----
    for(int e=tid;e<2048;e+=512){    // y: k = c2 (0..31)
      int c2=e>>6, j=e&63;
      Vsm[j][c2]=yb[(long)(c2*7+t)*HW_ + j];
    }
    float ft0=fsm[t][0],ft1=fsm[t][1],ft2=fsm[t][2],ft3=fsm[t][3],
          ft4=fsm[t][4],ft5=fsm[t][5],ft6=fsm[t][6];
    for(int e=tid;e<4096;e+=512){    // x_t: k=32+c ; xbar: k=96+c
      int c=e>>6, j=e&63;
      long base=(long)c*HW_ + j;
      float x0=xb[base], x1=xb[base+(long)C_*HW_], x2=xb[base+(long)(2*C_)*HW_],
            x3=xb[base+(long)(3*C_)*HW_], x4=xb[base+(long)(4*C_)*HW_],
            x5=xb[base+(long)(5*C_)*HW_], x6=xb[base+(long)(6*C_)*HW_];
      float xa=ft0*x0+ft1*x1+ft2*x2+ft3*x3+ft4*x4+ft5*x5+ft6*x6;
      float xt;
      switch(t){ case 0: xt=x0; break; case 1: xt=x1; break; case 2: xt=x2; break;
                 case 3: xt=x3; break; case 4: xt=x4; break; case 5: xt=x5; break;
                 default: xt=x6; }
      Vsm[j][32+c]=f2bf(xt);
      Vsm[j][96+c]=f2bf(xa);
    }
    __syncthreads();
    // ---- GEMM: D[32 out (oh)][16 px (pt)] over K=160 ----
    f32x4 D0=(f32x4){0.f,0.f,0.f,0.f}, D1=(f32x4){0.f,0.f,0.f,0.f};
    #pragma unroll
    for(int st=0;st<5;st++){
      union{ s16x8 v; uint2 d[2]; } a0,a1,bv;
      const u16* bp=&Vsm[px0+m][st*32+4*gq];
      bv.d[0]=*(const uint2*)bp;  bv.d[1]=*(const uint2*)(bp+16);
      const u16* ap0=&Msm[o0r+m][st*32+4*gq];
      a0.d[0]=*(const uint2*)ap0; a0.d[1]=*(const uint2*)(ap0+16);
      const u16* ap1=&Msm[o1r+m][st*32+4*gq];
      a1.d[0]=*(const uint2*)ap1; a1.d[1]=*(const uint2*)(ap1+16);
      D0=__builtin_amdgcn_mfma_f32_16x16x32_bf16(a0.v,bv.v,D0,0,0,0);
      D1=__builtin_amdgcn_mfma_f32_16x16x32_bf16(a1.v,bv.v,D1,0,0,0);
    }
    // ---- epilogue: + cst + residual x (f32), store ----
    #pragma unroll
    for(int r=0;r<4;r++){
      int c0=o0r+4*gq+r, c1=o1r+4*gq+r;
      long i0=(long)(t*C_+c0)*HW_ + px0+m;
      long i1=(long)(t*C_+c1)*HW_ + px0+m;
      ob[i0]=D0[r]+cst[c0]+xb[i0];
      ob[i1]=D1[r]+cst[c1]+xb[i1];
    }
  }
}

// ============================================================================
extern "C" void kernel_launch(void* const* d_in, const int* in_sizes, int n_in,
                              void* d_out, int out_size, void* d_ws, size_t ws_size,
                              hipStream_t stream)
{
  (void)in_sizes; (void)n_in; (void)out_size; (void)ws_size;
  const float* x      =(const float*)d_in[0];
  const float* hw_th_w=(const float*)d_in[1];  const float* hw_th_b=(const float*)d_in[2];
  const float* hw_ph_w=(const float*)d_in[3];  const float* hw_ph_b=(const float*)d_in[4];
  const float* hw_g_w =(const float*)d_in[5];  const float* hw_g_b =(const float*)d_in[6];
  const float* hw_z_w =(const float*)d_in[7];  const float* hw_z_b =(const float*)d_in[8];
  const float* c_th_w =(const float*)d_in[9];  const float* c_th_b =(const float*)d_in[10];
  const float* c_ph_w =(const float*)d_in[11]; const float* c_ph_b =(const float*)d_in[12];
  const float* c_g_w  =(const float*)d_in[13]; const float* c_g_b  =(const float*)d_in[14];
  const float* c_z_w  =(const float*)d_in[15]; const float* c_z_b  =(const float*)d_in[16];
  const float* t_th_w =(const float*)d_in[17]; const float* t_th_b =(const float*)d_in[18];
  const float* t_ph_w =(const float*)d_in[19]; const float* t_ph_b =(const float*)d_in[20];
  const float* t_g_w  =(const float*)d_in[21]; const float* t_g_b  =(const float*)d_in[22];
  const float* t_z_w  =(const float*)d_in[23]; const float* t_z_b  =(const float*)d_in[24];

  char* wsb=(char*)d_ws;
  u16*   th_hw=(u16*)  (wsb+OFF_TH_HW);
  u16*   ph_hw=(u16*)  (wsb+OFF_PH_HW);
  u16*   g_hw =(u16*)  (wsb+OFF_G_HW);
  u16*   y_hw =(u16*)  (wsb+OFF_Y_HW);
  float* th_t =(float*)(wsb+OFF_TH_T);
  float* ph_t =(float*)(wsb+OFF_PH_T);
  float* G    =(float*)(wsb+OFF_GRAM);
  float* srow =(float*)(wsb+OFF_SROW);
  float* Lt   =(float*)(wsb+OFF_LT);
  float* Mc   =(float*)(wsb+OFF_MC);
  float* vc   =(float*)(wsb+OFF_VC);
  float* Mt   =(float*)(wsb+OFF_MT);
  float* vt   =(float*)(wsb+OFF_VT);

  hipMemsetAsync(wsb+OFF_GRAM, 0, 65536+1024, stream);   // G + srow (atomic targets)

  k1_proj <<<448,256,0,stream>>>(x, hw_th_w,hw_th_b, hw_ph_w,hw_ph_b, hw_g_w,hw_g_b,
                                 t_th_w,t_th_b, t_ph_w,t_ph_b,
                                 th_hw,ph_hw,g_hw,th_t,ph_t);
  k3_gram <<<256,256,0,stream>>>(x,G,srow);
  k4_prep <<<4,  256,0,stream>>>(G,srow, c_th_w,c_th_b,c_ph_w,c_ph_b,c_g_w,c_g_b,c_z_w,c_z_b,
                                 t_g_w,t_g_b,t_z_w,t_z_b, Mc,vc,Mt,vt);
  k5_tlogit<<<196,256,0,stream>>>(th_t,ph_t,Lt);
  k2_attn <<<256,256,0,stream>>>(th_hw,ph_hw,g_hw,y_hw);
  k6_final<<<256,512,0,stream>>>(x,y_hw,Lt,Mc,vc,Mt,vt,hw_z_w,hw_z_b,(float*)d_out);
}